// Round 5
// baseline (260.708 us; speedup 1.0000x reference)
//
#include <hip/hip_runtime.h>

// Problem constants: B=16, K=8, C=64, L=2048
#define BB 16
#define KK 8
#define CC 64
#define LL 2048

constexpr int CL = CC * LL;                       // 131072 = 2^17 elems per batch
constexpr int NELEM = BB * CL;                    // 2,097,152
constexpr int NBLOCKS = NELEM / 256;              // 8192 blocks, 1 elem/thread

#define SIG_OFF 0.11920292202211755f              // 1 - sigmoid(2) = sigmoid(-2)
#define LOG_EPS -16.11809565095832f               // logf(1e-7)

__device__ __forceinline__ float frcp(float x) { return __builtin_amdgcn_rcpf(x); }

__global__ void init_sldj_kernel(const float* __restrict__ sldj_in,
                                 float* __restrict__ sldj_out) {
    int i = threadIdx.x;
    if (i < BB) sldj_out[i] = sldj_in[i];
}

// One element per thread, scalar dword loads:
//  - payload is 27 VGPRs (vs 108 for the float4 variant), so the FULL preload
//    fits under the 64-VGPR cap -> 8 waves/SIMD occupancy AND 27 loads in
//    flight per wave. R4 showed the quad variant stuck at VGPR=64 / occ 35%
//    with only ~10 float4s in flight (latency-bound, 86 us).
__global__ __launch_bounds__(256, 8) void coupling_kernel(
    const float* __restrict__ x,
    const float* __restrict__ a,
    const float* __restrict__ bv,
    const float* __restrict__ pi,
    const float* __restrict__ mu,
    const float* __restrict__ s,
    float* __restrict__ out,
    float* __restrict__ sldj_out) {

    const int idx = blockIdx.x * 256 + threadIdx.x;   // global element index
    const int b   = idx >> 17;                        // / CL
    const int kbase = (b << 20) + (idx & (CL - 1));   // b*K*CL + within-batch offset

    // ---- Phase 1: issue ALL 27 loads back-to-back ----
    const float xe = x[idx];
    const float ae = a[idx];
    const float be = bv[idx];

    float pv[KK], mv[KK], sv[KK];
#pragma unroll
    for (int k = 0; k < KK; ++k) {
        const int o = kbase + k * CL;
        pv[k] = pi[o];
        mv[k] = mu[o];
        sv[k] = s[o];
    }
    __builtin_amdgcn_sched_barrier(0);  // loads above, compute below

    // ---- Phase 2: linear-domain mixture math ----
    //   Spi = sum_k e^{pi_k}
    //   Nc  = sum_k e^{pi_k} * sigmoid(z_k)            -> u   = Nc/Spi
    //   N1  = sum_k e^{pi_k} * (1 - sigmoid(z_k))      -> 1-u = N1/Spi
    //   Np  = sum_k e^{pi_k} * e^{-s_k} * sig*(1-sig)  -> pdf = Np/Spi
    float Spi = 0.f, Nc = 0.f, N1 = 0.f, Np = 0.f;

#pragma unroll
    for (int k = 0; k < KK; ++k) {
        const float invstd = __expf(-sv[k]);
        const float z      = (xe - mv[k]) * invstd;

        // stable sigmoid via t = e^{-|z|}
        const float t  = __expf(-fabsf(z));
        const float r  = frcp(1.f + t);
        const float tr = t * r;
        const float sig  = (z >= 0.f) ? r  : tr;
        const float osig = (z >= 0.f) ? tr : r;

        const float ek = __expf(pv[k]);
        Spi += ek;
        Nc  += ek * sig;
        N1  += ek * osig;
        Np  += ek * invstd * sig * osig;
    }

    const float lSpi = __logf(Spi);
    const float lu   = fmaxf(__logf(Nc) - lSpi, LOG_EPS);
    const float lomu = fmaxf(__logf(N1) - lSpi, LOG_EPS);
    const float y        = lu - lomu;     // logit(u)
    const float ldj_term = -lu - lomu;
    const float log_pdf  = __logf(Np) - lSpi;

    // scale = sigmoid(a+2) + sigmoid(-2)
    const float av = ae + 2.f;
    const float t2 = __expf(-fabsf(av));
    const float r2 = frcp(1.f + t2);
    const float sc = ((av >= 0.f) ? r2 : t2 * r2) + SIG_OFF;

    out[idx] = (y + be) * sc;

    float contrib = log_pdf + ldj_term + __logf(sc);

    // ---- block reduction, one atomicAdd per block (block within batch b) ----
#pragma unroll
    for (int off = 32; off > 0; off >>= 1)
        contrib += __shfl_down(contrib, off, 64);

    __shared__ float wsum[4];
    const int lane = threadIdx.x & 63;
    const int wid  = threadIdx.x >> 6;
    if (lane == 0) wsum[wid] = contrib;
    __syncthreads();
    if (threadIdx.x == 0) {
        atomicAdd(&sldj_out[b], wsum[0] + wsum[1] + wsum[2] + wsum[3]);
    }
}

extern "C" void kernel_launch(void* const* d_in, const int* in_sizes, int n_in,
                              void* d_out, int out_size, void* d_ws, size_t ws_size,
                              hipStream_t stream) {
    const float* x    = (const float*)d_in[0];
    const float* a    = (const float*)d_in[1];
    const float* bv   = (const float*)d_in[2];
    const float* pi   = (const float*)d_in[3];
    const float* mu   = (const float*)d_in[4];
    const float* s    = (const float*)d_in[5];
    const float* sldj = (const float*)d_in[6];

    float* out      = (float*)d_out;
    float* sldj_out = out + (size_t)NELEM;  // outputs concat: out, then sldj

    init_sldj_kernel<<<1, 64, 0, stream>>>(sldj, sldj_out);
    coupling_kernel<<<NBLOCKS, 256, 0, stream>>>(x, a, bv, pi, mu, s, out, sldj_out);
}